// Round 7
// baseline (3357.295 us; speedup 1.0000x reference)
//
#include <hip/hip_runtime.h>
#include <hip/hip_bf16.h>
#include <cstdint>
#include <cstddef>

#define NNODES 100000
#define NEDGES 1600000
#define EPLUS  (NEDGES + NNODES)   // edges + self loops
#define NHEADS 4

typedef __hip_bfloat16 bf16;
typedef unsigned short u16;

// flag indices
#define F_X    0
#define F_WL1  1
#define F_BL1  2
#define F_WR1  3
#define F_BR1  4
#define F_ATT1 5
#define F_BO1  6
#define F_WL2  7
#define F_BL2  8
#define F_WR2  9
#define F_BR2  10
#define F_ATT2 11
#define F_BO2  12
#define F_EI64 13
#define F_BF16 14   // always 0: "this tensor is bf16" (internal buffers)

__device__ __forceinline__ float u2f(u16 s) { return __uint_as_float(((unsigned)s) << 16); }
__device__ __forceinline__ u16  f2u(float f) {
    return __bfloat16_as_ushort(__float2bfloat16(f));
}
// load element i of a tensor that is f32 (flag=1) or bf16 (flag=0)
__device__ __forceinline__ float ld_any(const void* p, long i, int f32) {
    return f32 ? ((const float*)p)[i] : u2f(((const u16*)p)[i]);
}

// ---- dtype detection for every float tensor + edge_index width ------------
// f32 data: even-indexed u16 = low mantissa bits -> garbage exponent field.
// bf16 data (~N(0,sigma)): exponent field in a narrow band.
__global__ void detect_all(const u16* x, const u16* Wl1, const u16* bl1,
                           const u16* Wr1, const u16* br1, const u16* att1,
                           const u16* bo1, const u16* Wl2, const u16* bl2,
                           const u16* Wr2, const u16* br2, const u16* att2,
                           const u16* bo2, const int* ei, int* flags) {
    const int t = threadIdx.x;
    const u16* ptrs[13] = {x, Wl1, bl1, Wr1, br1, att1, bo1,
                           Wl2, bl2, Wr2, br2, att2, bo2};
    const int cnts[13] = {NNODES * 64, 64 * 64, 64, 64 * 64, 64, 64, 64,
                          64 * 256, 256, 64 * 256, 256, 256, 64};
    if (t < 13) {
        const u16* p = ptrs[t];
        const int cnt = cnts[t];
        int weird = 0, n = 0;
        for (int k = 0; k < 128; ++k) {
            int idx = 2 * k;
            if (idx >= cnt) break;
            u16 v = p[idx];
            n++;
            int ex = (v >> 7) & 0xFF;
            if (v != 0 && (ex < 96 || ex > 143)) weird++;
        }
        flags[t] = (weird * 4 > n) ? 1 : 0;   // 1 => f32
    } else if (t == 13) {
        int any = 0;
        for (int k = 0; k < 64; ++k) any |= ei[2 * k + 1];
        flags[F_EI64] = (any == 0) ? 1 : 0;   // 1 => int64
    } else if (t == 14) {
        flags[F_BF16] = 0;
    }
}

__device__ __forceinline__ void edge_sd(const int* __restrict__ ei, int i64,
                                        int e, int& s, int& d) {
    if (e >= NEDGES) { s = d = e - NEDGES; return; }   // self loop
    if (i64) {
        const long long* p = (const long long*)ei;
        s = (int)p[e]; d = (int)p[NEDGES + e];
    } else {
        s = ei[e]; d = ei[NEDGES + e];
    }
    s = min(max(s, 0), NNODES - 1);   // safety clamp
    d = min(max(d, 0), NNODES - 1);
}

// ------- GEMM: out[N,M] = x[N,64] @ W[64,M] + b; col-blocked; bf16 out -----
template<int M, int CB>
__global__ __launch_bounds__(256)
void gemm_k64(const void* __restrict__ x, const void* __restrict__ W,
              const void* __restrict__ b, const int* __restrict__ flags,
              int fxi, int fwi, int fbi, u16* __restrict__ out) {
    __shared__ float Ws[64 * CB];
    __shared__ float xs[32 * 65];
    __shared__ float bs[CB];
    const int fx = flags[fxi], fw = flags[fwi], fb = flags[fbi];
    const int tid = threadIdx.x;
    const int col0 = blockIdx.y * CB;
    for (int i = tid; i < 64 * CB; i += 256) {
        int k = i / CB, c = i % CB;
        Ws[i] = ld_any(W, (long)k * M + col0 + c, fw);
    }
    if (tid < CB) bs[tid] = ld_any(b, col0 + tid, fb);
    const int row0 = blockIdx.x * 32;
    for (int i = tid; i < 32 * 64; i += 256) {
        int r = i >> 6, c = i & 63;
        int row = row0 + r;
        xs[r * 65 + c] = (row < NNODES) ? ld_any(x, (long)row * 64 + c, fx) : 0.f;
    }
    __syncthreads();
    for (int t = tid; t < 32 * CB; t += 256) {
        int r = t / CB, c = t % CB;
        int row = row0 + r;
        if (row >= NNODES) continue;
        float acc = bs[c];
#pragma unroll
        for (int k = 0; k < 64; ++k)
            acc = fmaf(xs[r * 65 + k], Ws[k * CB + c], acc);
        out[(size_t)row * M + col0 + c] = f2u(acc);
    }
}

// ---- per-edge attention: ex = exp(score), denom[d,h] += ex ----------------
// scores bounded (|score| <~ 5) so softmax max-shift cancels; clamp for safety
template<int HC>
__global__ __launch_bounds__(256)
void score_kernel(const u16* __restrict__ xl, const u16* __restrict__ xr,
                  const int* __restrict__ ei, const int* __restrict__ flags,
                  const void* __restrict__ att, int fai,
                  float* __restrict__ exscore, float* __restrict__ denom) {
    constexpr int VEC = HC / 64;
    __shared__ float att_s[HC];
    const int tid = threadIdx.x;
    if (tid < HC) att_s[tid] = ld_any(att, tid, flags[fai]);
    __syncthreads();
    const int e = blockIdx.x * 4 + (tid >> 6);
    if (e >= EPLUS) return;
    const int lane = tid & 63;
    int s, d;
    edge_sd(ei, flags[F_EI64], e, s, d);
    const u16* lp = xl + (size_t)s * HC + lane * VEC;
    const u16* rp = xr + (size_t)d * HC + lane * VEC;
    float lv[VEC], rv[VEC];
    if constexpr (VEC == 4) {
        ushort4 a = *(const ushort4*)lp;
        lv[0]=u2f(a.x); lv[1]=u2f(a.y); lv[2]=u2f(a.z); lv[3]=u2f(a.w);
        ushort4 c = *(const ushort4*)rp;
        rv[0]=u2f(c.x); rv[1]=u2f(c.y); rv[2]=u2f(c.z); rv[3]=u2f(c.w);
    } else {
        lv[0] = u2f(lp[0]); rv[0] = u2f(rp[0]);
    }
    float sum = 0.f;
#pragma unroll
    for (int j = 0; j < VEC; ++j) {
        float v = lv[j] + rv[j];
        v = (v > 0.f) ? v : 0.2f * v;               // leaky_relu 0.2
        sum = fmaf(v, att_s[lane * VEC + j], sum);
    }
#pragma unroll
    for (int off = 8; off >= 1; off >>= 1)
        sum += __shfl_xor(sum, off, 64);
    if ((lane & 15) == 0) {
        int h = lane >> 4;
        sum = fminf(fmaxf(sum, -60.f), 60.f);       // no inf possible
        float ex = expf(sum);
        exscore[(size_t)e * NHEADS + h] = ex;
        atomicAdd(&denom[d * NHEADS + h], ex);
    }
}

// ---------------- weighted scatter aggregation -----------------------------
template<int HC, bool MEAN>
__global__ __launch_bounds__(256)
void agg_kernel(const u16* __restrict__ xl, const int* __restrict__ ei,
                const int* __restrict__ flags, const float* __restrict__ exscore,
                const float* __restrict__ denom, float* __restrict__ acc) {
    constexpr int VEC = HC / 64;
    const int tid = threadIdx.x;
    const int e = blockIdx.x * 4 + (tid >> 6);
    if (e >= EPLUS) return;
    const int lane = tid & 63;
    int s, d;
    edge_sd(ei, flags[F_EI64], e, s, d);
    const int h = lane >> 4;
    const float alpha = exscore[(size_t)e * NHEADS + h] /
                        (denom[d * NHEADS + h] + 1e-16f);
    const u16* lp = xl + (size_t)s * HC + lane * VEC;
    float v[VEC];
    if constexpr (VEC == 4) {
        ushort4 a = *(const ushort4*)lp;
        v[0]=u2f(a.x); v[1]=u2f(a.y); v[2]=u2f(a.z); v[3]=u2f(a.w);
    } else {
        v[0] = u2f(lp[0]);
    }
#pragma unroll
    for (int j = 0; j < VEC; ++j) v[j] *= alpha;
    if constexpr (MEAN) {
#pragma unroll
        for (int j = 0; j < VEC; ++j) {
            v[j] += __shfl_xor(v[j], 16, 64);
            v[j] += __shfl_xor(v[j], 32, 64);
        }
        if (lane < 16) {
#pragma unroll
            for (int j = 0; j < VEC; ++j)
                atomicAdd(&acc[(size_t)d * 64 + lane * VEC + j], v[j]);
        }
    } else {
        atomicAdd(&acc[(size_t)d * 64 + lane], v[0]);
    }
}

// ------- bias + relu (+ mean scale); TO = u16 (bf16) or float --------------
template<bool MEAN, typename TO>
__global__ __launch_bounds__(256)
void finalize_kernel(const float* __restrict__ acc, const void* __restrict__ bo,
                     const int* __restrict__ flags, int fbi,
                     TO* __restrict__ out) {
    const int i = blockIdx.x * 256 + threadIdx.x;
    if (i >= NNODES * 64) return;
    float v = acc[i];
    if (MEAN) v *= 0.25f;
    v += ld_any(bo, i & 63, flags[fbi]);
    v = (v > 0.f) ? v : 0.f;
    if constexpr (sizeof(TO) == 2) out[i] = f2u(v);
    else                           out[i] = v;
}

// ---------------- diagnostics: plant f32 code into out[0] if unhealthy -----
__global__ void check_kernel(const u16* hbuf, const u16* xlb,
                             const float* denom, const float* accb,
                             const int* flags, float* out) {
    __shared__ float red[256];
    float s0 = 0, s1 = 0, s2 = 0, s3 = 0;
    for (int i = threadIdx.x; i < 4096; i += 256) {
        s0 += fabsf(u2f(hbuf[i]));
        s1 += fabsf(u2f(xlb[i]));
        s3 += fabsf(accb[i]);
    }
    for (int i = threadIdx.x; i < 16; i += 256) s2 += denom[i];
    float in[4] = {s0, s1, s2, s3};
    float tot[4];
    for (int q = 0; q < 4; ++q) {
        red[threadIdx.x] = in[q];
        __syncthreads();
        for (int off = 128; off; off >>= 1) {
            if (threadIdx.x < off) red[threadIdx.x] += red[threadIdx.x + off];
            __syncthreads();
        }
        tot[q] = red[0];
        __syncthreads();
    }
    if (threadIdx.x == 0) {
        float code = 0.f;
        const float base[4] = {2000.f, 3000.f, 4000.f, 5000.f};
        for (int q = 0; q < 4; ++q) {
            bool nan = (tot[q] != tot[q]);
            bool zer = (tot[q] == 0.f);
            if (nan || zer) {
                float c = base[q] + (nan ? 500.f : 0.f)
                        + 100.f * (float)flags[F_X] + 10.f * (float)flags[F_EI64];
                code = fmaxf(code, c);
            }
        }
        if (code > 0.f) out[0] = code;
    }
}

__global__ void plant_kernel(float* out, float code) {
    if (code > 0.f) out[0] = code;
}

extern "C" void kernel_launch(void* const* d_in, const int* in_sizes, int n_in,
                              void* d_out, int out_size, void* d_ws, size_t ws_size,
                              hipStream_t stream) {
    // ---- host-side slot mapping by element counts (robust to slot shifts) ----
    int ix = -1, iei = -1;
    int i4096[2], i16384[2], i64s[5], i256[3];
    int c4 = 0, c16 = 0, c64 = 0, c256 = 0;
    bool extra = false;
    for (int i = 0; i < n_in; ++i) {
        int sz = in_sizes[i];
        if (sz == 6400000)      { if (ix < 0) ix = i; else extra = true; }
        else if (sz == 3200000) { if (iei < 0) iei = i; else extra = true; }
        else if (sz == 4096)    { if (c4  < 2) i4096[c4]  = i; c4++;  }
        else if (sz == 16384)   { if (c16 < 2) i16384[c16] = i; c16++; }
        else if (sz == 64)      { if (c64 < 5) i64s[c64]  = i; c64++; }
        else if (sz == 256)     { if (c256 < 3) i256[c256] = i; c256++; }
        else if (sz == 100000 || sz == 1) { /* frame_mask or scalar: unused */ }
        else extra = true;
    }
    bool ok = (ix >= 0) && (iei >= 0) && (c4 == 2) && (c16 == 2)
              && (c64 == 5) && (c256 == 3) && !extra;
    float code = 0.f;
    if (!ok) {
        code = 50000.f + 100.f * (float)n_in + 10.f * (float)(c64 > 9 ? 9 : c64)
             + (float)(c256 > 9 ? 9 : c256);
        ix = 0; iei = 1;
        i4096[0] = 3;  i4096[1] = 5;
        i64s[0] = 4; i64s[1] = 6; i64s[2] = 7; i64s[3] = 8; i64s[4] = 14;
        i16384[0] = 9; i16384[1] = 11;
        i256[0] = 10; i256[1] = 12; i256[2] = 13;
    }
    const size_t need = 169600064;
    if (ws_size < need) {
        float c2 = 60000.f + (float)(ws_size >> 20);
        code = (c2 > code) ? c2 : code;
    }

    const u16* x    = (const u16*)d_in[ix];
    const int* ei   = (const int*)d_in[iei];
    const u16* Wl1  = (const u16*)d_in[i4096[0]];
    const u16* Wr1  = (const u16*)d_in[i4096[1]];
    const u16* bl1  = (const u16*)d_in[i64s[0]];
    const u16* br1  = (const u16*)d_in[i64s[1]];
    const u16* att1 = (const u16*)d_in[i64s[2]];
    const u16* bo1  = (const u16*)d_in[i64s[3]];
    const u16* bo2  = (const u16*)d_in[i64s[4]];
    const u16* Wl2  = (const u16*)d_in[i16384[0]];
    const u16* Wr2  = (const u16*)d_in[i16384[1]];
    const u16* bl2  = (const u16*)d_in[i256[0]];
    const u16* br2  = (const u16*)d_in[i256[1]];
    const u16* att2 = (const u16*)d_in[i256[2]];

    // ---- workspace layout (bytes), ~169.6 MB ----
    char* ws = (char*)d_ws;
    u16*   xlb   = (u16*)(ws);                        // N*256 bf16 = 51.2 MB
    u16*   xrb   = (u16*)(ws + 51200000);             // N*256 bf16 = 51.2 MB
    u16*   hbuf  = (u16*)(ws + 102400000);            // N*64  bf16 = 12.8 MB
    float* score = (float*)(ws + 115200000);          // EPLUS*4 f32 = 27.2 MB
    float* denom = (float*)(ws + 142400000);          // N*4 f32 = 1.6 MB
    float* accb  = (float*)(ws + 144000000);          // N*64 f32 = 25.6 MB
    int*   flags = (int*)(ws + 169600000);            // 16 ints

    const int rows_grid = (NNODES + 31) / 32;        // 3125
    const int edge_grid = (EPLUS + 3) / 4;           // 425000
    const int fin_grid  = (NNODES * 64 + 255) / 256;

    detect_all<<<1, 64, 0, stream>>>(x, Wl1, bl1, Wr1, br1, att1, bo1,
                                     Wl2, bl2, Wr2, br2, att2, bo2, ei, flags);

    // ---------------- layer 1 (64 -> 4x16, concat) ----------------
    (void)hipMemsetAsync(denom, 0, (size_t)NNODES * NHEADS * 4, stream);
    (void)hipMemsetAsync(accb,  0, (size_t)NNODES * 64 * 4, stream);
    gemm_k64<64, 64><<<dim3(rows_grid, 1), 256, 0, stream>>>(
        x, Wl1, bl1, flags, F_X, F_WL1, F_BL1, xlb);
    gemm_k64<64, 64><<<dim3(rows_grid, 1), 256, 0, stream>>>(
        x, Wr1, br1, flags, F_X, F_WR1, F_BR1, xrb);
    score_kernel<64><<<edge_grid, 256, 0, stream>>>(
        xlb, xrb, ei, flags, att1, F_ATT1, score, denom);
    agg_kernel<64, false><<<edge_grid, 256, 0, stream>>>(
        xlb, ei, flags, score, denom, accb);
    finalize_kernel<false, u16><<<fin_grid, 256, 0, stream>>>(
        accb, bo1, flags, F_BO1, hbuf);

    // ---------------- layer 2 (64 -> 4x64, mean) ----------------
    (void)hipMemsetAsync(denom, 0, (size_t)NNODES * NHEADS * 4, stream);
    (void)hipMemsetAsync(accb,  0, (size_t)NNODES * 64 * 4, stream);
    gemm_k64<256, 128><<<dim3(rows_grid, 2), 256, 0, stream>>>(
        hbuf, Wl2, bl2, flags, F_BF16, F_WL2, F_BL2, xlb);
    gemm_k64<256, 128><<<dim3(rows_grid, 2), 256, 0, stream>>>(
        hbuf, Wr2, br2, flags, F_BF16, F_WR2, F_BR2, xrb);
    score_kernel<256><<<edge_grid, 256, 0, stream>>>(
        xlb, xrb, ei, flags, att2, F_ATT2, score, denom);
    agg_kernel<256, true><<<edge_grid, 256, 0, stream>>>(
        xlb, ei, flags, score, denom, accb);
    finalize_kernel<true, float><<<fin_grid, 256, 0, stream>>>(
        accb, bo2, flags, F_BO2, (float*)d_out);

    // ---------------- diagnostics (no-op when healthy) ----------------
    check_kernel<<<1, 256, 0, stream>>>(hbuf, xlb, denom, accb, flags, (float*)d_out);
    plant_kernel<<<1, 1, 0, stream>>>((float*)d_out, code);
}

// Round 8
// 1187.318 us; speedup vs baseline: 2.8276x; 2.8276x over previous
//
#include <hip/hip_runtime.h>
#include <hip/hip_bf16.h>
#include <cstdint>
#include <cstddef>

#define NNODES 100000
#define NEDGES 1600000
#define EPLUS  (NEDGES + NNODES)   // edges + self loops
#define NHEADS 4
#define NB     ((NNODES + 255) / 256)   // 391 scan blocks

typedef __hip_bfloat16 bf16;
typedef unsigned short u16;

// flag indices
#define F_X    0
#define F_WL1  1
#define F_BL1  2
#define F_WR1  3
#define F_BR1  4
#define F_ATT1 5
#define F_BO1  6
#define F_WL2  7
#define F_BL2  8
#define F_WR2  9
#define F_BR2  10
#define F_ATT2 11
#define F_BO2  12
#define F_EI64 13
#define F_BF16 14   // always 0: "this tensor is bf16" (internal buffers)

__device__ __forceinline__ float u2f(u16 s) { return __uint_as_float(((unsigned)s) << 16); }
__device__ __forceinline__ u16  f2u(float f) {
    return __bfloat16_as_ushort(__float2bfloat16(f));
}
// load element i of a tensor that is f32 (flag=1) or bf16 (flag=0)
__device__ __forceinline__ float ld_any(const void* p, long i, int f32) {
    return f32 ? ((const float*)p)[i] : u2f(((const u16*)p)[i]);
}

// ---- dtype detection for every float tensor + edge_index width ------------
__global__ void detect_all(const u16* x, const u16* Wl1, const u16* bl1,
                           const u16* Wr1, const u16* br1, const u16* att1,
                           const u16* bo1, const u16* Wl2, const u16* bl2,
                           const u16* Wr2, const u16* br2, const u16* att2,
                           const u16* bo2, const int* ei, int* flags) {
    const int t = threadIdx.x;
    const u16* ptrs[13] = {x, Wl1, bl1, Wr1, br1, att1, bo1,
                           Wl2, bl2, Wr2, br2, att2, bo2};
    const int cnts[13] = {NNODES * 64, 64 * 64, 64, 64 * 64, 64, 64, 64,
                          64 * 256, 256, 64 * 256, 256, 256, 64};
    if (t < 13) {
        const u16* p = ptrs[t];
        const int cnt = cnts[t];
        int weird = 0, n = 0;
        for (int k = 0; k < 128; ++k) {
            int idx = 2 * k;
            if (idx >= cnt) break;
            u16 v = p[idx];
            n++;
            int ex = (v >> 7) & 0xFF;
            if (v != 0 && (ex < 96 || ex > 143)) weird++;
        }
        flags[t] = (weird * 4 > n) ? 1 : 0;   // 1 => f32
    } else if (t == 13) {
        int any = 0;
        for (int k = 0; k < 64; ++k) any |= ei[2 * k + 1];
        flags[F_EI64] = (any == 0) ? 1 : 0;   // 1 => int64
    } else if (t == 14) {
        flags[F_BF16] = 0;
    }
}

__device__ __forceinline__ void edge_sd(const int* __restrict__ ei, int i64,
                                        int e, int& s, int& d) {
    if (e >= NEDGES) { s = d = e - NEDGES; return; }   // self loop
    if (i64) {
        const long long* p = (const long long*)ei;
        s = (int)p[e]; d = (int)p[NEDGES + e];
    } else {
        s = ei[e]; d = ei[NEDGES + e];
    }
    s = min(max(s, 0), NNODES - 1);
    d = min(max(d, 0), NNODES - 1);
}

// ------- GEMM: out[N,M] = x[N,64] @ W[64,M] + b; col-blocked; bf16 out -----
template<int M, int CB>
__global__ __launch_bounds__(256)
void gemm_k64(const void* __restrict__ x, const void* __restrict__ W,
              const void* __restrict__ b, const int* __restrict__ flags,
              int fxi, int fwi, int fbi, u16* __restrict__ out) {
    __shared__ float Ws[64 * CB];
    __shared__ float xs[32 * 65];
    __shared__ float bs[CB];
    const int fx = flags[fxi], fw = flags[fwi], fb = flags[fbi];
    const int tid = threadIdx.x;
    const int col0 = blockIdx.y * CB;
    for (int i = tid; i < 64 * CB; i += 256) {
        int k = i / CB, c = i % CB;
        Ws[i] = ld_any(W, (long)k * M + col0 + c, fw);
    }
    if (tid < CB) bs[tid] = ld_any(b, col0 + tid, fb);
    const int row0 = blockIdx.x * 32;
    for (int i = tid; i < 32 * 64; i += 256) {
        int r = i >> 6, c = i & 63;
        int row = row0 + r;
        xs[r * 65 + c] = (row < NNODES) ? ld_any(x, (long)row * 64 + c, fx) : 0.f;
    }
    __syncthreads();
    for (int t = tid; t < 32 * CB; t += 256) {
        int r = t / CB, c = t % CB;
        int row = row0 + r;
        if (row >= NNODES) continue;
        float acc = bs[c];
#pragma unroll
        for (int k = 0; k < 64; ++k)
            acc = fmaf(xs[r * 65 + k], Ws[k * CB + c], acc);
        out[(size_t)row * M + col0 + c] = f2u(acc);
    }
}

// ---------------- CSR build: histogram / scan / fill -----------------------
__global__ __launch_bounds__(256)
void hist_kernel(const int* __restrict__ ei, const int* __restrict__ flags,
                 int* __restrict__ cnt) {
    const int e = blockIdx.x * 256 + threadIdx.x;
    if (e >= NEDGES) return;
    int d;
    if (flags[F_EI64]) d = (int)((const long long*)ei)[NEDGES + e];
    else               d = ei[NEDGES + e];
    d = min(max(d, 0), NNODES - 1);
    atomicAdd(&cnt[d], 1);
}

// inclusive scan of (cnt[i]+1) within each 256-block; partials to tmp, sums to bsum
__global__ __launch_bounds__(256)
void scan1_kernel(const int* __restrict__ cnt, int* __restrict__ tmp,
                  int* __restrict__ bsum) {
    __shared__ int sh[256];
    const int idx = blockIdx.x * 256 + threadIdx.x;
    int v = (idx < NNODES) ? cnt[idx] + 1 : 0;
    sh[threadIdx.x] = v;
    __syncthreads();
    for (int off = 1; off < 256; off <<= 1) {
        int t = (threadIdx.x >= off) ? sh[threadIdx.x - off] : 0;
        __syncthreads();
        sh[threadIdx.x] += t;
        __syncthreads();
    }
    if (idx < NNODES) tmp[idx] = sh[threadIdx.x];
    if (threadIdx.x == 255) bsum[blockIdx.x] = sh[255];
}

__global__ __launch_bounds__(512)
void scan2_kernel(int* __restrict__ bsum) {   // inclusive scan of NB elems
    __shared__ int sh[512];
    const int t = threadIdx.x;
    sh[t] = (t < NB) ? bsum[t] : 0;
    __syncthreads();
    for (int off = 1; off < 512; off <<= 1) {
        int v = (t >= off) ? sh[t - off] : 0;
        __syncthreads();
        sh[t] += v;
        __syncthreads();
    }
    if (t < NB) bsum[t] = sh[t];
}

__global__ __launch_bounds__(256)
void scan3_kernel(const int* __restrict__ tmp, const int* __restrict__ bsum,
                  int* __restrict__ row_ptr) {
    const int idx = blockIdx.x * 256 + threadIdx.x;
    if (idx < NNODES) {
        int off = (blockIdx.x > 0) ? bsum[blockIdx.x - 1] : 0;
        row_ptr[idx + 1] = tmp[idx] + off;
    }
    if (idx == 0) row_ptr[0] = 0;
}

__global__ __launch_bounds__(256)
void fill_kernel(const int* __restrict__ ei, const int* __restrict__ flags,
                 const int* __restrict__ row_ptr, int* __restrict__ cur,
                 int* __restrict__ csr_src) {
    const int e = blockIdx.x * 256 + threadIdx.x;
    if (e >= EPLUS) return;
    int s, d;
    edge_sd(ei, flags[F_EI64], e, s, d);
    int slot = row_ptr[d] + atomicAdd(&cur[d], 1);
    csr_src[slot] = s;
}

// ---------------- fused per-destination GATv2 ------------------------------
// one wave per dst node; lanes 16h..16h+15 cover head h (VEC channels each).
// walks CSR edges: score -> exp -> online denom + weighted acc in registers;
// single coalesced row write at the end. No f32 atomics anywhere.
template<int HC, bool MEAN, typename TO>
__global__ __launch_bounds__(256)
void fused_gat(const u16* __restrict__ xl, const u16* __restrict__ xr,
               const int* __restrict__ row_ptr, const int* __restrict__ csr_src,
               const void* __restrict__ att, const void* __restrict__ bo,
               const int* __restrict__ flags, int fai, int fbi,
               TO* __restrict__ out) {
    constexpr int VEC = HC / 64;
    const int d = blockIdx.x * 4 + (threadIdx.x >> 6);
    if (d >= NNODES) return;
    const int lane = threadIdx.x & 63;
    const int fatt = flags[fai];

    float attv[VEC], rv[VEC];
#pragma unroll
    for (int j = 0; j < VEC; ++j)
        attv[j] = ld_any(att, lane * VEC + j, fatt);
    if constexpr (VEC == 4) {
        ushort4 r = *(const ushort4*)(xr + (size_t)d * HC + lane * 4);
        rv[0]=u2f(r.x); rv[1]=u2f(r.y); rv[2]=u2f(r.z); rv[3]=u2f(r.w);
    } else {
        rv[0] = u2f(xr[(size_t)d * HC + lane]);
    }

    const int beg = row_ptr[d], end = row_ptr[d + 1];   // end>beg (self loop)
    float denom = 1e-16f;
    float acc[VEC];
#pragma unroll
    for (int j = 0; j < VEC; ++j) acc[j] = 0.f;

    // software-pipelined gather: row i+1 load overlaps compute of row i
    int s_cur = csr_src[beg];
    ushort4 a4; u16 a1;
    if constexpr (VEC == 4)
        a4 = *(const ushort4*)(xl + (size_t)s_cur * HC + lane * 4);
    else
        a1 = xl[(size_t)s_cur * HC + lane];

    for (int i = beg; i < end; ++i) {
        float lv[VEC];
        if constexpr (VEC == 4) {
            lv[0]=u2f(a4.x); lv[1]=u2f(a4.y); lv[2]=u2f(a4.z); lv[3]=u2f(a4.w);
        } else {
            lv[0] = u2f(a1);
        }
        if (i + 1 < end) {
            int s_nxt = csr_src[i + 1];
            if constexpr (VEC == 4)
                a4 = *(const ushort4*)(xl + (size_t)s_nxt * HC + lane * 4);
            else
                a1 = xl[(size_t)s_nxt * HC + lane];
        }
        float part = 0.f;
#pragma unroll
        for (int j = 0; j < VEC; ++j) {
            float v = lv[j] + rv[j];
            v = (v > 0.f) ? v : 0.2f * v;              // leaky_relu 0.2
            part = fmaf(v, attv[j], part);
        }
#pragma unroll
        for (int off = 8; off >= 1; off >>= 1)
            part += __shfl_xor(part, off, 64);         // reduce within head
        float ex = __expf(fminf(fmaxf(part, -60.f), 60.f));
        denom += ex;
#pragma unroll
        for (int j = 0; j < VEC; ++j)
            acc[j] = fmaf(ex, lv[j], acc[j]);
    }

    const float inv = 1.f / denom;
    if constexpr (MEAN) {
#pragma unroll
        for (int j = 0; j < VEC; ++j) {
            acc[j] *= inv;
            acc[j] += __shfl_xor(acc[j], 16, 64);      // sum 4 heads
            acc[j] += __shfl_xor(acc[j], 32, 64);
        }
        if (lane < 16) {
            const int fbo = flags[fbi];
            float4 o;
            float* op = (float*)&o;
#pragma unroll
            for (int j = 0; j < VEC; ++j) {
                float v = acc[j] * 0.25f + ld_any(bo, lane * 4 + j, fbo);
                op[j] = (v > 0.f) ? v : 0.f;
            }
            *(float4*)((float*)out + (size_t)d * 64 + lane * 4) = o;
        }
    } else {
        const int fbo = flags[fbi];
        float v = acc[0] * inv + ld_any(bo, lane, fbo);
        v = (v > 0.f) ? v : 0.f;
        ((u16*)out)[(size_t)d * 64 + lane] = f2u(v);
    }
}

// plant a host-computed code (mapping / ws_size failure); no-op when healthy
__global__ void plant_kernel(float* out, float code) {
    if (code > 0.f) out[0] = code;
}

extern "C" void kernel_launch(void* const* d_in, const int* in_sizes, int n_in,
                              void* d_out, int out_size, void* d_ws, size_t ws_size,
                              hipStream_t stream) {
    // ---- host-side slot mapping by element counts (robust to slot shifts) ----
    int ix = -1, iei = -1;
    int i4096[2], i16384[2], i64s[5], i256[3];
    int c4 = 0, c16 = 0, c64 = 0, c256 = 0;
    bool extra = false;
    for (int i = 0; i < n_in; ++i) {
        int sz = in_sizes[i];
        if (sz == 6400000)      { if (ix < 0) ix = i; else extra = true; }
        else if (sz == 3200000) { if (iei < 0) iei = i; else extra = true; }
        else if (sz == 4096)    { if (c4  < 2) i4096[c4]  = i; c4++;  }
        else if (sz == 16384)   { if (c16 < 2) i16384[c16] = i; c16++; }
        else if (sz == 64)      { if (c64 < 5) i64s[c64]  = i; c64++; }
        else if (sz == 256)     { if (c256 < 3) i256[c256] = i; c256++; }
        else if (sz == 100000 || sz == 1) { /* frame_mask / scalar: unused */ }
        else extra = true;
    }
    bool ok = (ix >= 0) && (iei >= 0) && (c4 == 2) && (c16 == 2)
              && (c64 == 5) && (c256 == 3) && !extra;
    float code = 0.f;
    if (!ok) {
        code = 50000.f + 100.f * (float)n_in + 10.f * (float)(c64 > 9 ? 9 : c64)
             + (float)(c256 > 9 ? 9 : c256);
        ix = 0; iei = 1;
        i4096[0] = 3;  i4096[1] = 5;
        i64s[0] = 4; i64s[1] = 6; i64s[2] = 7; i64s[3] = 8; i64s[4] = 14;
        i16384[0] = 9; i16384[1] = 11;
        i256[0] = 10; i256[1] = 12; i256[2] = 13;
    }

    const u16* x    = (const u16*)d_in[ix];
    const int* ei   = (const int*)d_in[iei];
    const u16* Wl1  = (const u16*)d_in[i4096[0]];
    const u16* Wr1  = (const u16*)d_in[i4096[1]];
    const u16* bl1  = (const u16*)d_in[i64s[0]];
    const u16* br1  = (const u16*)d_in[i64s[1]];
    const u16* att1 = (const u16*)d_in[i64s[2]];
    const u16* bo1  = (const u16*)d_in[i64s[3]];
    const u16* bo2  = (const u16*)d_in[i64s[4]];
    const u16* Wl2  = (const u16*)d_in[i16384[0]];
    const u16* Wr2  = (const u16*)d_in[i16384[1]];
    const u16* bl2  = (const u16*)d_in[i256[0]];
    const u16* br2  = (const u16*)d_in[i256[1]];
    const u16* att2 = (const u16*)d_in[i256[2]];

    // ---- workspace layout (bytes), ~123.3 MB ----
    char* ws = (char*)d_ws;
    u16* xlb     = (u16*)(ws);                    // N*256 bf16 = 51.2 MB
    u16* xrb     = (u16*)(ws + 51200000);         // N*256 bf16 = 51.2 MB
    u16* hbuf    = (u16*)(ws + 102400000);        // N*64  bf16 = 12.8 MB
    int* row_ptr = (int*)(ws + 115200000);        // (N+1)*4
    int* cnt     = (int*)(ws + 115600016);        // N*4  (cnt, then reused as cursor)
    int* tmp     = (int*)(ws + 116000016);        // N*4
    int* bsum    = (int*)(ws + 116400016);        // NB*4
    int* csr_src = (int*)(ws + 116401600);        // EPLUS*4 = 6.8 MB
    int* flags   = (int*)(ws + 123201600);        // 16 ints
    const size_t need = 123201664;
    if (ws_size < need) {
        float c2 = 60000.f + (float)(ws_size >> 20);
        code = (c2 > code) ? c2 : code;
    }

    const int rows_grid = (NNODES + 31) / 32;     // 3125
    const int node_grid = (NNODES + 3) / 4;       // 25000 (4 waves/block)
    const int e_grid    = (NEDGES + 255) / 256;
    const int ep_grid   = (EPLUS + 255) / 256;

    detect_all<<<1, 64, 0, stream>>>(x, Wl1, bl1, Wr1, br1, att1, bo1,
                                     Wl2, bl2, Wr2, br2, att2, bo2, ei, flags);

    // ---------------- CSR build (shared by both layers) ----------------
    (void)hipMemsetAsync(cnt, 0, (size_t)NNODES * 4, stream);
    hist_kernel<<<e_grid, 256, 0, stream>>>(ei, flags, cnt);
    scan1_kernel<<<NB, 256, 0, stream>>>(cnt, tmp, bsum);
    scan2_kernel<<<1, 512, 0, stream>>>(bsum);
    scan3_kernel<<<NB, 256, 0, stream>>>(tmp, bsum, row_ptr);
    (void)hipMemsetAsync(cnt, 0, (size_t)NNODES * 4, stream);   // reuse as cursor
    fill_kernel<<<ep_grid, 256, 0, stream>>>(ei, flags, row_ptr, cnt, csr_src);

    // ---------------- layer 1 (64 -> 4x16, concat) ----------------
    gemm_k64<64, 64><<<dim3(rows_grid, 1), 256, 0, stream>>>(
        x, Wl1, bl1, flags, F_X, F_WL1, F_BL1, xlb);
    gemm_k64<64, 64><<<dim3(rows_grid, 1), 256, 0, stream>>>(
        x, Wr1, br1, flags, F_X, F_WR1, F_BR1, xrb);
    fused_gat<64, false, u16><<<node_grid, 256, 0, stream>>>(
        xlb, xrb, row_ptr, csr_src, att1, bo1, flags, F_ATT1, F_BO1, hbuf);

    // ---------------- layer 2 (64 -> 4x64, mean) ----------------
    gemm_k64<256, 128><<<dim3(rows_grid, 2), 256, 0, stream>>>(
        hbuf, Wl2, bl2, flags, F_BF16, F_WL2, F_BL2, xlb);
    gemm_k64<256, 128><<<dim3(rows_grid, 2), 256, 0, stream>>>(
        hbuf, Wr2, br2, flags, F_BF16, F_WR2, F_BR2, xrb);
    fused_gat<256, true, float><<<node_grid, 256, 0, stream>>>(
        xlb, xrb, row_ptr, csr_src, att2, bo2, flags, F_ATT2, F_BO2, (float*)d_out);

    plant_kernel<<<1, 1, 0, stream>>>((float*)d_out, code);
}

// Round 9
// 731.766 us; speedup vs baseline: 4.5879x; 1.6225x over previous
//
#include <hip/hip_runtime.h>
#include <hip/hip_bf16.h>
#include <cstdint>
#include <cstddef>

#define NNODES 100000
#define NEDGES 1600000
#define EPLUS  (NEDGES + NNODES)   // edges + self loops
#define NHEADS 4
#define NB     ((NNODES + 255) / 256)   // 391 scan blocks

typedef __hip_bfloat16 bf16;
typedef unsigned short u16;
typedef __attribute__((ext_vector_type(8))) short bf16x8;
typedef __attribute__((ext_vector_type(4))) float f32x4;

// flag indices
#define F_X    0
#define F_WL1  1
#define F_BL1  2
#define F_WR1  3
#define F_BR1  4
#define F_ATT1 5
#define F_BO1  6
#define F_WL2  7
#define F_BL2  8
#define F_WR2  9
#define F_BR2  10
#define F_ATT2 11
#define F_BO2  12
#define F_EI64 13

__device__ __forceinline__ float u2f(u16 s) { return __uint_as_float(((unsigned)s) << 16); }
__device__ __forceinline__ u16  f2u(float f) {
    return __bfloat16_as_ushort(__float2bfloat16(f));
}
__device__ __forceinline__ float ld_any(const void* p, long i, int f32) {
    return f32 ? ((const float*)p)[i] : u2f(((const u16*)p)[i]);
}

// ---- dtype detection for every float tensor + edge_index width ------------
__global__ void detect_all(const u16* x, const u16* Wl1, const u16* bl1,
                           const u16* Wr1, const u16* br1, const u16* att1,
                           const u16* bo1, const u16* Wl2, const u16* bl2,
                           const u16* Wr2, const u16* br2, const u16* att2,
                           const u16* bo2, const int* ei, int* flags) {
    const int t = threadIdx.x;
    const u16* ptrs[13] = {x, Wl1, bl1, Wr1, br1, att1, bo1,
                           Wl2, bl2, Wr2, br2, att2, bo2};
    const int cnts[13] = {NNODES * 64, 64 * 64, 64, 64 * 64, 64, 64, 64,
                          64 * 256, 256, 64 * 256, 256, 256, 64};
    if (t < 13) {
        const u16* p = ptrs[t];
        const int cnt = cnts[t];
        int weird = 0, n = 0;
        for (int k = 0; k < 128; ++k) {
            int idx = 2 * k;
            if (idx >= cnt) break;
            u16 v = p[idx];
            n++;
            int ex = (v >> 7) & 0xFF;
            if (v != 0 && (ex < 96 || ex > 143)) weird++;
        }
        flags[t] = (weird * 4 > n) ? 1 : 0;   // 1 => f32
    } else if (t == 13) {
        int any = 0;
        for (int k = 0; k < 64; ++k) any |= ei[2 * k + 1];
        flags[F_EI64] = (any == 0) ? 1 : 0;   // 1 => int64
    }
}

__device__ __forceinline__ void edge_sd(const int* __restrict__ ei, int i64,
                                        int e, int& s, int& d) {
    if (e >= NEDGES) { s = d = e - NEDGES; return; }   // self loop
    if (i64) {
        const long long* p = (const long long*)ei;
        s = (int)p[e]; d = (int)p[NEDGES + e];
    } else {
        s = ei[e]; d = ei[NEDGES + e];
    }
    s = min(max(s, 0), NNODES - 1);
    d = min(max(d, 0), NNODES - 1);
}

// ---------------- input canonicalization to bf16 ---------------------------
__global__ __launch_bounds__(256)
void conv_x(const void* __restrict__ x, const int* __restrict__ flags,
            u16* __restrict__ xc) {
    const long i4 = ((long)blockIdx.x * 256 + threadIdx.x) * 4;
    if (i4 >= (long)NNODES * 64) return;
    if (flags[F_X]) {
        const float4 v = *(const float4*)((const float*)x + i4);
        ushort4 o; o.x = f2u(v.x); o.y = f2u(v.y); o.z = f2u(v.z); o.w = f2u(v.w);
        *(ushort4*)(xc + i4) = o;
    } else {
        *(ushort4*)(xc + i4) = *(const ushort4*)((const u16*)x + i4);
    }
}

// W[64][M] -> Wt[M][64] bf16
template<int M>
__global__ __launch_bounds__(256)
void conv_w(const void* __restrict__ W, const int* __restrict__ flags, int fwi,
            u16* __restrict__ wt) {
    const int idx = blockIdx.x * 256 + threadIdx.x;
    if (idx >= M * 64) return;
    const int m = idx >> 6, k = idx & 63;
    wt[idx] = f2u(ld_any(W, (long)k * M + m, flags[fwi]));
}

// biases: [0:64) bl1, [64:128) br1, [128:384) bl2, [384:640) br2
__global__ void conv_b(const void* bl1, const void* br1, const void* bl2,
                       const void* br2, const int* __restrict__ flags,
                       u16* __restrict__ out) {
    const int t = threadIdx.x;
    if (t < 64)       out[t] = f2u(ld_any(bl1, t,       flags[F_BL1]));
    else if (t < 128) out[t] = f2u(ld_any(br1, t - 64,  flags[F_BR1]));
    else if (t < 384) out[t] = f2u(ld_any(bl2, t - 128, flags[F_BL2]));
    else if (t < 640) out[t] = f2u(ld_any(br2, t - 384, flags[F_BR2]));
}

// ---------------- CSR build: histogram / scan / fill -----------------------
__global__ __launch_bounds__(256)
void hist_kernel(const int* __restrict__ ei, const int* __restrict__ flags,
                 int* __restrict__ cnt) {
    const int e = blockIdx.x * 256 + threadIdx.x;
    if (e >= NEDGES) return;
    int d;
    if (flags[F_EI64]) d = (int)((const long long*)ei)[NEDGES + e];
    else               d = ei[NEDGES + e];
    d = min(max(d, 0), NNODES - 1);
    atomicAdd(&cnt[d], 1);
}

__global__ __launch_bounds__(256)
void scan1_kernel(const int* __restrict__ cnt, int* __restrict__ tmp,
                  int* __restrict__ bsum) {
    __shared__ int sh[256];
    const int idx = blockIdx.x * 256 + threadIdx.x;
    int v = (idx < NNODES) ? cnt[idx] + 1 : 0;
    sh[threadIdx.x] = v;
    __syncthreads();
    for (int off = 1; off < 256; off <<= 1) {
        int t = (threadIdx.x >= off) ? sh[threadIdx.x - off] : 0;
        __syncthreads();
        sh[threadIdx.x] += t;
        __syncthreads();
    }
    if (idx < NNODES) tmp[idx] = sh[threadIdx.x];
    if (threadIdx.x == 255) bsum[blockIdx.x] = sh[255];
}

__global__ __launch_bounds__(512)
void scan2_kernel(int* __restrict__ bsum) {
    __shared__ int sh[512];
    const int t = threadIdx.x;
    sh[t] = (t < NB) ? bsum[t] : 0;
    __syncthreads();
    for (int off = 1; off < 512; off <<= 1) {
        int v = (t >= off) ? sh[t - off] : 0;
        __syncthreads();
        sh[t] += v;
        __syncthreads();
    }
    if (t < NB) bsum[t] = sh[t];
}

__global__ __launch_bounds__(256)
void scan3_kernel(const int* __restrict__ tmp, const int* __restrict__ bsum,
                  int* __restrict__ row_ptr) {
    const int idx = blockIdx.x * 256 + threadIdx.x;
    if (idx < NNODES) {
        int off = (blockIdx.x > 0) ? bsum[blockIdx.x - 1] : 0;
        row_ptr[idx + 1] = tmp[idx] + off;
    }
    if (idx == 0) row_ptr[0] = 0;
}

__global__ __launch_bounds__(256)
void fill_kernel(const int* __restrict__ ei, const int* __restrict__ flags,
                 const int* __restrict__ row_ptr, int* __restrict__ cur,
                 int* __restrict__ csr_src) {
    const int e = blockIdx.x * 256 + threadIdx.x;
    if (e >= EPLUS) return;
    int s, d;
    edge_sd(ei, flags[F_EI64], e, s, d);
    int slot = row_ptr[d] + atomicAdd(&cur[d], 1);
    csr_src[slot] = s;
}

// ---------------- MFMA GEMM: out[N,M] = xc[N,64] @ W + b, bf16 out ---------
// A-frag: A[m=lane&15][k=quad*8+j] from xc rows (16B vector loads)
// B-frag: B[k=quad*8+j][n=lane&15] from Wt[M][64]
// C/D:    row=quad*4+r, col=lane&15  (verified layout)
// waves split M into 4 col-blocks; no LDS, no barriers.
template<int M, int RPB>
__global__ __launch_bounds__(256)
void gemm_mfma(const u16* __restrict__ xc, const u16* __restrict__ wt,
               const u16* __restrict__ bc, u16* __restrict__ out) {
    constexpr int MT = RPB / 16;            // m-tiles per wave
    constexpr int NT = M / 64;              // n-tiles per wave
    const int wave = threadIdx.x >> 6;
    const int lane = threadIdx.x & 63;
    const int quad = lane >> 4;
    const int l16  = lane & 15;
    const int row0 = blockIdx.x * RPB;
    const int col0 = wave * (M / 4);

    bf16x8 bfrag[NT][2];
#pragma unroll
    for (int nt = 0; nt < NT; ++nt)
#pragma unroll
        for (int c = 0; c < 2; ++c)
            bfrag[nt][c] = *(const bf16x8*)(wt +
                ((size_t)(col0 + nt * 16 + l16) * 64 + c * 32 + quad * 8));

    f32x4 acc[MT][NT];
#pragma unroll
    for (int mt = 0; mt < MT; ++mt)
#pragma unroll
        for (int nt = 0; nt < NT; ++nt)
            acc[mt][nt] = f32x4{0.f, 0.f, 0.f, 0.f};

#pragma unroll
    for (int mt = 0; mt < MT; ++mt) {
        int row = row0 + mt * 16 + l16;
        row = (row < NNODES) ? row : (NNODES - 1);   // clamp; stores guarded
#pragma unroll
        for (int c = 0; c < 2; ++c) {
            bf16x8 afrag = *(const bf16x8*)(xc + ((size_t)row * 64 + c * 32 + quad * 8));
#pragma unroll
            for (int nt = 0; nt < NT; ++nt)
                acc[mt][nt] = __builtin_amdgcn_mfma_f32_16x16x32_bf16(
                    afrag, bfrag[nt][c], acc[mt][nt], 0, 0, 0);
        }
    }

#pragma unroll
    for (int mt = 0; mt < MT; ++mt) {
#pragma unroll
        for (int nt = 0; nt < NT; ++nt) {
            const int col = col0 + nt * 16 + l16;
            const float bias = u2f(bc[col]);
#pragma unroll
            for (int r = 0; r < 4; ++r) {
                const int row = row0 + mt * 16 + quad * 4 + r;
                if (row < NNODES)
                    out[(size_t)row * M + col] = f2u(acc[mt][nt][r] + bias);
            }
        }
    }
}

// ---------------- fused per-destination GATv2 ------------------------------
template<int HC, bool MEAN, typename TO>
__global__ __launch_bounds__(256)
void fused_gat(const u16* __restrict__ xl, const u16* __restrict__ xr,
               const int* __restrict__ row_ptr, const int* __restrict__ csr_src,
               const void* __restrict__ att, const void* __restrict__ bo,
               const int* __restrict__ flags, int fai, int fbi,
               TO* __restrict__ out) {
    constexpr int VEC = HC / 64;
    const int d = blockIdx.x * 4 + (threadIdx.x >> 6);
    if (d >= NNODES) return;
    const int lane = threadIdx.x & 63;
    const int fatt = flags[fai];

    float attv[VEC], rv[VEC];
#pragma unroll
    for (int j = 0; j < VEC; ++j)
        attv[j] = ld_any(att, lane * VEC + j, fatt);
    if constexpr (VEC == 4) {
        ushort4 r = *(const ushort4*)(xr + (size_t)d * HC + lane * 4);
        rv[0]=u2f(r.x); rv[1]=u2f(r.y); rv[2]=u2f(r.z); rv[3]=u2f(r.w);
    } else {
        rv[0] = u2f(xr[(size_t)d * HC + lane]);
    }

    const int beg = row_ptr[d], end = row_ptr[d + 1];
    float denom = 1e-16f;
    float acc[VEC];
#pragma unroll
    for (int j = 0; j < VEC; ++j) acc[j] = 0.f;

    int s_cur = csr_src[beg];
    ushort4 a4; u16 a1;
    if constexpr (VEC == 4)
        a4 = *(const ushort4*)(xl + (size_t)s_cur * HC + lane * 4);
    else
        a1 = xl[(size_t)s_cur * HC + lane];

    for (int i = beg; i < end; ++i) {
        float lv[VEC];
        if constexpr (VEC == 4) {
            lv[0]=u2f(a4.x); lv[1]=u2f(a4.y); lv[2]=u2f(a4.z); lv[3]=u2f(a4.w);
        } else {
            lv[0] = u2f(a1);
        }
        if (i + 1 < end) {
            int s_nxt = csr_src[i + 1];
            if constexpr (VEC == 4)
                a4 = *(const ushort4*)(xl + (size_t)s_nxt * HC + lane * 4);
            else
                a1 = xl[(size_t)s_nxt * HC + lane];
        }
        float part = 0.f;
#pragma unroll
        for (int j = 0; j < VEC; ++j) {
            float v = lv[j] + rv[j];
            v = (v > 0.f) ? v : 0.2f * v;              // leaky_relu 0.2
            part = fmaf(v, attv[j], part);
        }
#pragma unroll
        for (int off = 8; off >= 1; off >>= 1)
            part += __shfl_xor(part, off, 64);
        float ex = __expf(fminf(fmaxf(part, -60.f), 60.f));
        denom += ex;
#pragma unroll
        for (int j = 0; j < VEC; ++j)
            acc[j] = fmaf(ex, lv[j], acc[j]);
    }

    const float inv = 1.f / denom;
    if constexpr (MEAN) {
#pragma unroll
        for (int j = 0; j < VEC; ++j) {
            acc[j] *= inv;
            acc[j] += __shfl_xor(acc[j], 16, 64);
            acc[j] += __shfl_xor(acc[j], 32, 64);
        }
        if (lane < 16) {
            const int fbo = flags[fbi];
            float4 o;
            float* op = (float*)&o;
#pragma unroll
            for (int j = 0; j < VEC; ++j) {
                float v = acc[j] * 0.25f + ld_any(bo, lane * 4 + j, fbo);
                op[j] = (v > 0.f) ? v : 0.f;
            }
            *(float4*)((float*)out + (size_t)d * 64 + lane * 4) = o;
        }
    } else {
        const int fbo = flags[fbi];
        float v = acc[0] * inv + ld_any(bo, lane, fbo);
        v = (v > 0.f) ? v : 0.f;
        ((u16*)out)[(size_t)d * 64 + lane] = f2u(v);
    }
}

__global__ void plant_kernel(float* out, float code) {
    if (code > 0.f) out[0] = code;
}

extern "C" void kernel_launch(void* const* d_in, const int* in_sizes, int n_in,
                              void* d_out, int out_size, void* d_ws, size_t ws_size,
                              hipStream_t stream) {
    // ---- host-side slot mapping by element counts ----
    int ix = -1, iei = -1;
    int i4096[2], i16384[2], i64s[5], i256[3];
    int c4 = 0, c16 = 0, c64 = 0, c256 = 0;
    bool extra = false;
    for (int i = 0; i < n_in; ++i) {
        int sz = in_sizes[i];
        if (sz == 6400000)      { if (ix < 0) ix = i; else extra = true; }
        else if (sz == 3200000) { if (iei < 0) iei = i; else extra = true; }
        else if (sz == 4096)    { if (c4  < 2) i4096[c4]  = i; c4++;  }
        else if (sz == 16384)   { if (c16 < 2) i16384[c16] = i; c16++; }
        else if (sz == 64)      { if (c64 < 5) i64s[c64]  = i; c64++; }
        else if (sz == 256)     { if (c256 < 3) i256[c256] = i; c256++; }
        else if (sz == 100000 || sz == 1) { /* frame_mask / scalar: unused */ }
        else extra = true;
    }
    bool ok = (ix >= 0) && (iei >= 0) && (c4 == 2) && (c16 == 2)
              && (c64 == 5) && (c256 == 3) && !extra;
    float code = 0.f;
    if (!ok) {
        code = 50000.f + 100.f * (float)n_in;
        ix = 0; iei = 1;
        i4096[0] = 3;  i4096[1] = 5;
        i64s[0] = 4; i64s[1] = 6; i64s[2] = 7; i64s[3] = 8; i64s[4] = 14;
        i16384[0] = 9; i16384[1] = 11;
        i256[0] = 10; i256[1] = 12; i256[2] = 13;
    }

    const u16* x    = (const u16*)d_in[ix];
    const int* ei   = (const int*)d_in[iei];
    const u16* Wl1  = (const u16*)d_in[i4096[0]];
    const u16* Wr1  = (const u16*)d_in[i4096[1]];
    const u16* bl1  = (const u16*)d_in[i64s[0]];
    const u16* br1  = (const u16*)d_in[i64s[1]];
    const u16* att1 = (const u16*)d_in[i64s[2]];
    const u16* bo1  = (const u16*)d_in[i64s[3]];
    const u16* bo2  = (const u16*)d_in[i64s[4]];
    const u16* Wl2  = (const u16*)d_in[i16384[0]];
    const u16* Wr2  = (const u16*)d_in[i16384[1]];
    const u16* bl2  = (const u16*)d_in[i256[0]];
    const u16* br2  = (const u16*)d_in[i256[1]];
    const u16* att2 = (const u16*)d_in[i256[2]];

    // ---- workspace layout (bytes), ~136.1 MB ----
    char* ws = (char*)d_ws;
    u16* xlb     = (u16*)(ws);                    // N*256 bf16 = 51.2 MB
    u16* xrb     = (u16*)(ws + 51200000);         // N*256 bf16 = 51.2 MB
    u16* hbuf    = (u16*)(ws + 102400000);        // N*64  bf16 = 12.8 MB
    u16* xc      = (u16*)(ws + 115200000);        // N*64  bf16 = 12.8 MB
    int* row_ptr = (int*)(ws + 128000000);        // (N+1)*4
    int* cnt     = (int*)(ws + 128400016);        // N*4
    int* tmp     = (int*)(ws + 128800016);        // N*4
    int* bsum    = (int*)(ws + 129201600 - 1584); // NB*4 (fits pre-pad gap)
    int* csr_src = (int*)(ws + 129201600);        // EPLUS*4 = 6.8 MB
    u16* wt1l    = (u16*)(ws + 136001600);        // 64*64 bf16
    u16* wt1r    = (u16*)(ws + 136009792);
    u16* wt2l    = (u16*)(ws + 136017984);        // 256*64 bf16
    u16* wt2r    = (u16*)(ws + 136050752);
    u16* bcs     = (u16*)(ws + 136083520);        // 640 bf16
    int* flags   = (int*)(ws + 136084800);        // 16 ints
    const size_t need = 136084864;
    if (ws_size < need) {
        float c2 = 60000.f + (float)(ws_size >> 20);
        code = (c2 > code) ? c2 : code;
    }

    const int node_grid = (NNODES + 3) / 4;       // 25000
    const int e_grid    = (NEDGES + 255) / 256;
    const int ep_grid   = (EPLUS + 255) / 256;

    detect_all<<<1, 64, 0, stream>>>(x, Wl1, bl1, Wr1, br1, att1, bo1,
                                     Wl2, bl2, Wr2, br2, att2, bo2, ei, flags);

    // ---- canonicalize GEMM inputs to bf16 ----
    conv_x<<<(NNODES * 64 / 4 + 255) / 256, 256, 0, stream>>>(x, flags, xc);
    conv_w<64><<<16, 256, 0, stream>>>(Wl1, flags, F_WL1, wt1l);
    conv_w<64><<<16, 256, 0, stream>>>(Wr1, flags, F_WR1, wt1r);
    conv_w<256><<<64, 256, 0, stream>>>(Wl2, flags, F_WL2, wt2l);
    conv_w<256><<<64, 256, 0, stream>>>(Wr2, flags, F_WR2, wt2r);
    conv_b<<<1, 640, 0, stream>>>(bl1, br1, bl2, br2, flags, bcs);

    // ---- CSR build (shared by both layers) ----
    (void)hipMemsetAsync(cnt, 0, (size_t)NNODES * 4, stream);
    hist_kernel<<<e_grid, 256, 0, stream>>>(ei, flags, cnt);
    scan1_kernel<<<NB, 256, 0, stream>>>(cnt, tmp, bsum);
    scan2_kernel<<<1, 512, 0, stream>>>(bsum);
    scan3_kernel<<<NB, 256, 0, stream>>>(tmp, bsum, row_ptr);
    (void)hipMemsetAsync(cnt, 0, (size_t)NNODES * 4, stream);
    fill_kernel<<<ep_grid, 256, 0, stream>>>(ei, flags, row_ptr, cnt, csr_src);

    // ---- layer 1 (64 -> 4x16, concat) ----
    gemm_mfma<64, 128><<<(NNODES + 127) / 128, 256, 0, stream>>>(xc, wt1l, bcs,       xlb);
    gemm_mfma<64, 128><<<(NNODES + 127) / 128, 256, 0, stream>>>(xc, wt1r, bcs + 64,  xrb);
    fused_gat<64, false, u16><<<node_grid, 256, 0, stream>>>(
        xlb, xrb, row_ptr, csr_src, att1, bo1, flags, F_ATT1, F_BO1, hbuf);

    // ---- layer 2 (64 -> 4x64, mean) ----
    gemm_mfma<256, 64><<<(NNODES + 63) / 64, 256, 0, stream>>>(hbuf, wt2l, bcs + 128, xlb);
    gemm_mfma<256, 64><<<(NNODES + 63) / 64, 256, 0, stream>>>(hbuf, wt2r, bcs + 384, xrb);
    fused_gat<256, true, float><<<node_grid, 256, 0, stream>>>(
        xlb, xrb, row_ptr, csr_src, att2, bo2, flags, F_ATT2, F_BO2, (float*)d_out);

    plant_kernel<<<1, 1, 0, stream>>>((float*)d_out, code);
}